// Round 8
// baseline (385.262 us; speedup 1.0000x reference)
//
#include <hip/hip_runtime.h>
#include <hip/hip_cooperative_groups.h>

namespace cg = cooperative_groups;

#define NEG_SLOPE 0.01f
#define BSHIFT 8          // nodes per dst-bucket = 256
#define BMASK 255
#define BMAX 512          // bucket count bound (supports N <= 131072)
#define CAPB 5120         // static per-bucket capacity (avg 4092, +16 sigma)

typedef __attribute__((ext_vector_type(8))) short bf16x8;
typedef __attribute__((ext_vector_type(4))) float f32x4;
typedef __attribute__((ext_vector_type(2))) float f32x2;
typedef __attribute__((ext_vector_type(4))) unsigned u32x4;

// fp32 -> bf16 (RNE, normals only — fine for this data)
static __device__ inline unsigned short f2b(float f) {
    unsigned u = __builtin_bit_cast(unsigned, f);
    return (unsigned short)((u + 0x7FFF + ((u >> 16) & 1)) >> 16);
}
static __device__ inline float b2f_lo(unsigned u) {
    return __builtin_bit_cast(float, u << 16);
}
static __device__ inline float b2f_hi(unsigned u) {
    return __builtin_bit_cast(float, u & 0xFFFF0000u);
}

// ---------------------------------------------------------------------------
// Front: feat fp32->bf16 (blocks [0,nf4)); W transpose->bf16 + bcursor zero
// (blocks [nf4, nf4+64)).
// ---------------------------------------------------------------------------
__global__ __launch_bounds__(256) void front_kernel(const float* __restrict__ feat,
                                                    unsigned short* __restrict__ featb,
                                                    long long nfeat,
                                                    const float* __restrict__ W1,
                                                    const float* __restrict__ W2,
                                                    unsigned short* __restrict__ Wt1,
                                                    unsigned short* __restrict__ Wt2,
                                                    int* __restrict__ bcursor,
                                                    int B, int nf4) {
    const int bx = blockIdx.x;
    const int t = threadIdx.x;
    if (bx < nf4) {
        long long i = ((long long)bx * 256 + t) * 4;
        if (i < nfeat) {
            float4 v = *(const float4*)(feat + i);
            ushort4 o;
            o.x = f2b(v.x); o.y = f2b(v.y); o.z = f2b(v.z); o.w = f2b(v.w);
            *(ushort4*)(featb + i) = o;
        }
        return;
    }
    const int bx2 = bx - nf4;            // 0..63
    if (bx2 < 2) {
        int z = bx2 * 256 + t;
        if (z < BMAX) bcursor[z] = 0;
    }
    int i = bx2 * 256 + t;               // 0..16383
    int n = i & 127, k = i >> 7;
    Wt1[n * 128 + k] = f2b(W1[k * 128 + n]);
    Wt2[n * 128 + k] = f2b(W2[k * 128 + n]);
}

// ---------------------------------------------------------------------------
// Cooperative CSR build (replaces bscatter + bfinal, eliminates the pairs
// round-trip):
//   phase 1: per-block LDS histogram of dst-buckets -> one global atomicAdd
//            per (block,bucket) reserves a base -> scatter packed entries
//            (src 24b | local-dst 8b) DIRECTLY into static csr regions.
//   grid.sync()
//   phase 2: block b stages its bucket (<=20 KB) into LDS, counting-sorts by
//            local dst entirely in LDS (histogram -> scan -> scatter into a
//            2nd LDS buffer), writes offsets/degs, writes the sorted src
//            values back FULLY COALESCED.
// LDS 43 KB -> 3 blocks/CU co-residency; grid = B (<=512) blocks.
// ---------------------------------------------------------------------------
__global__ __launch_bounds__(256) void csr_build(const int* __restrict__ src,
                                                 const int* __restrict__ dst,
                                                 int* __restrict__ bcursor,
                                                 unsigned* __restrict__ csrU,
                                                 int* __restrict__ offsets,
                                                 int* __restrict__ degs,
                                                 int E, int B, int N) {
    __shared__ int smem[2 * CAPB + 512];          // 43008 B
    const int t = threadIdx.x;
    const int b = blockIdx.x;

    // ---- phase 1: scatter edges into static bucket regions ----
    int* h = smem;            // BMAX ints
    int* base = smem + BMAX;  // BMAX ints
    for (int i = t; i < B; i += 256) h[i] = 0;
    __syncthreads();
    const int chunk = (E + (int)gridDim.x - 1) / (int)gridDim.x;
    const int e0 = b * chunk;
    const int e1 = min(e0 + chunk, E);
    for (int e = e0 + t; e < e1; e += 256)
        atomicAdd(&h[dst[e] >> BSHIFT], 1);
    __syncthreads();
    for (int i = t; i < B; i += 256) {
        int c = h[i];
        base[i] = c ? atomicAdd(&bcursor[i], c) : 0;
    }
    __syncthreads();
    for (int i = t; i < B; i += 256) h[i] = base[i];
    __syncthreads();
    for (int e = e0 + t; e < e1; e += 256) {
        int d = dst[e];
        int bb = d >> BSHIFT;
        int pos = atomicAdd(&h[bb], 1);
        if (pos < CAPB)
            csrU[(size_t)bb * CAPB + pos] = (unsigned)src[e] | ((unsigned)(d & BMASK) << 24);
    }

    cg::this_grid().sync();

    // ---- phase 2: per-bucket LDS counting sort ----
    unsigned* stage  = (unsigned*)smem;           // CAPB
    unsigned* sorted = (unsigned*)smem + CAPB;    // CAPB
    int* h2  = smem + 2 * CAPB;                   // 256
    int* cur = h2 + 256;                          // 256
    const int cnt = min(bcursor[b], CAPB);
    unsigned* __restrict__ cb = csrU + (size_t)b * CAPB;
    for (int e = t; e < cnt; e += 256) stage[e] = cb[e];
    h2[t] = 0;
    __syncthreads();
    for (int e = t; e < cnt; e += 256)
        atomicAdd(&h2[stage[e] >> 24], 1);
    __syncthreads();
    int v = h2[t];
    for (int d = 1; d < 256; d <<= 1) {
        int u = (t >= d) ? h2[t - d] : 0;
        __syncthreads();
        h2[t] += u;
        __syncthreads();
    }
    const int prefix = h2[t] - v;                 // exclusive prefix in bucket
    const int node = (b << BSHIFT) + t;
    if (node < N) {
        offsets[node] = b * CAPB + prefix;
        degs[node] = v;
    }
    cur[t] = prefix;
    __syncthreads();
    for (int e = t; e < cnt; e += 256) {
        unsigned pr = stage[e];
        int pos = atomicAdd(&cur[pr >> 24], 1);
        sorted[pos] = pr & 0xFFFFFFu;
    }
    __syncthreads();
    for (int e = t; e < cnt; e += 256) cb[e] = sorted[e];   // coalesced
}

// ---------------------------------------------------------------------------
// Aggregate (r5/r7 structure — proven 60 us): one wave per node; 4 lane-
// groups of 16, one 256B row per group per gather instruction. All index
// traffic on the SCALAR path (node wave-uniform -> s_load for offsets/degs/
// csr). Exact gather counts, wave-uniform branches, 4 gathers (4 KB) in
// flight via inline-asm global_load_dwordx4. Self gather exec-masked to
// group 0. Waves retire after ONE node -> continuous fresh-wave stream.
// ---------------------------------------------------------------------------
static __device__ inline f32x2 up2(unsigned u) {
    return (f32x2){ b2f_lo(u), b2f_hi(u) };
}

#define GATHER(dst, off) \
    asm volatile("global_load_dwordx4 %0, %1, %2" : "=v"(dst) : "v"(off), "s"(xc))
#define ACC4(u) do { A0 += up2((u).x); A1 += up2((u).y); \
                     A2 += up2((u).z); A3 += up2((u).w); } while (0)
#define ACCM(u, mk) do { \
    A0 += up2((u).x & (mk)); A1 += up2((u).y & (mk)); \
    A2 += up2((u).z & (mk)); A3 += up2((u).w & (mk)); } while (0)

static __device__ __forceinline__ unsigned rowsel(int g, unsigned poff,
                                                  int i0, int i1, int i2, int i3) {
    int s01 = (g & 1) ? i1 : i0;
    int s23 = (g & 1) ? i3 : i2;
    int s = (g & 2) ? s23 : s01;
    return ((unsigned)s << 8) | poff;
}

__global__ __launch_bounds__(256) void aggregate_kernel(const unsigned short* __restrict__ xb,
                                                        const int* __restrict__ offsets,
                                                        const int* __restrict__ degs,
                                                        const int* __restrict__ csr,
                                                        unsigned short* __restrict__ Hb,
                                                        int N) {
    const int node = (blockIdx.x * blockDim.x + threadIdx.x) >> 6;
    if (node >= N) return;
    const int lane = threadIdx.x & 63;
    const int g = lane >> 4;                              // neighbor slot 0..3
    const unsigned poff = (unsigned)((lane & 15) << 4);   // 16B chunk in row
    const char* __restrict__ xc = (const char*)xb;

    // wave-uniform node -> scalar offsets/degs/csr loads (SMEM path)
    const int nu = __builtin_amdgcn_readfirstlane(node);
    const int start = __builtin_amdgcn_readfirstlane(offsets[nu]);
    const int deg   = __builtin_amdgcn_readfirstlane(degs[nu]);
    const int rounds = deg >> 2;
    const int tailn  = deg & 3;

    // self gather: group 0 only; consumed post-reduce
    u32x4 vs = (u32x4){0, 0, 0, 0};
    if (g == 0) GATHER(vs, ((unsigned)nu << 8) | poff);

    f32x2 A0 = {0.f, 0.f}, A1 = {0.f, 0.f}, A2 = {0.f, 0.f}, A3 = {0.f, 0.f};

    int r = 0;
    while (r + 4 <= rounds) {             // wave-uniform
        const int p = start + (r << 2);
        int i0  = csr[p +  0], i1  = csr[p +  1], i2  = csr[p +  2], i3  = csr[p +  3];
        int i4  = csr[p +  4], i5  = csr[p +  5], i6  = csr[p +  6], i7  = csr[p +  7];
        int i8  = csr[p +  8], i9  = csr[p +  9], i10 = csr[p + 10], i11 = csr[p + 11];
        int i12 = csr[p + 12], i13 = csr[p + 13], i14 = csr[p + 14], i15 = csr[p + 15];
        unsigned a0 = rowsel(g, poff, i0,  i1,  i2,  i3);
        unsigned a1 = rowsel(g, poff, i4,  i5,  i6,  i7);
        unsigned a2 = rowsel(g, poff, i8,  i9,  i10, i11);
        unsigned a3 = rowsel(g, poff, i12, i13, i14, i15);
        __builtin_amdgcn_sched_barrier(0);
        u32x4 v0, v1, v2, v3;
        GATHER(v0, a0); GATHER(v1, a1); GATHER(v2, a2); GATHER(v3, a3);
        asm volatile("s_waitcnt vmcnt(0)" ::: "memory");
        __builtin_amdgcn_sched_barrier(0);
        ACC4(v0); ACC4(v1); ACC4(v2); ACC4(v3);
        r += 4;
    }

    // remainder rounds (0..3) + tail, exact counts, wave-uniform branches
    const int rr = rounds - r;
    const int p = start + (r << 2);
    u32x4 v0, v1, v2, vt;
    if (rr >= 1) {
        int i0 = csr[p + 0], i1 = csr[p + 1], i2 = csr[p + 2], i3 = csr[p + 3];
        GATHER(v0, rowsel(g, poff, i0, i1, i2, i3));
    }
    if (rr >= 2) {
        int i0 = csr[p + 4], i1 = csr[p + 5], i2 = csr[p + 6], i3 = csr[p + 7];
        GATHER(v1, rowsel(g, poff, i0, i1, i2, i3));
    }
    if (rr >= 3) {
        int i0 = csr[p + 8], i1 = csr[p + 9], i2 = csr[p + 10], i3 = csr[p + 11];
        GATHER(v2, rowsel(g, poff, i0, i1, i2, i3));
    }
    const unsigned mt = (g < tailn) ? ~0u : 0u;
    if (tailn) {
        const int q = start + (rounds << 2);
        int t0 = csr[q];
        int t1 = (tailn > 1) ? csr[q + 1] : t0;
        int t2 = (tailn > 2) ? csr[q + 2] : t0;
        GATHER(vt, rowsel(g, poff, t0, t1, t2, t0));
    }
    asm volatile("s_waitcnt vmcnt(0)" ::: "memory");
    __builtin_amdgcn_sched_barrier(0);
    if (rr >= 1) ACC4(v0);
    if (rr >= 2) ACC4(v1);
    if (rr >= 3) ACC4(v2);
    if (tailn) ACCM(vt, mt);

    // combine the 4 lane-groups: butterfly leaves full sum in every lane
    float a[8];
    a[0] = A0.x; a[1] = A0.y; a[2] = A1.x; a[3] = A1.y;
    a[4] = A2.x; a[5] = A2.y; a[6] = A3.x; a[7] = A3.y;
#pragma unroll
    for (int i = 0; i < 8; ++i) {
        a[i] += __shfl_xor(a[i], 16);
        a[i] += __shfl_xor(a[i], 32);
    }
    // self term (group 0 only holds it; group 0 is the storing group)
    a[0] += b2f_lo(vs.x); a[1] += b2f_hi(vs.x);
    a[2] += b2f_lo(vs.y); a[3] += b2f_hi(vs.y);
    a[4] += b2f_lo(vs.z); a[5] += b2f_hi(vs.z);
    a[6] += b2f_lo(vs.w); a[7] += b2f_hi(vs.w);

    const float inv = 1.0f / (float)(deg + 1);
    if (g == 0) {
        uint4 o;
        o.x = (unsigned)f2b(a[0] * inv) | ((unsigned)f2b(a[1] * inv) << 16);
        o.y = (unsigned)f2b(a[2] * inv) | ((unsigned)f2b(a[3] * inv) << 16);
        o.z = (unsigned)f2b(a[4] * inv) | ((unsigned)f2b(a[5] * inv) << 16);
        o.w = (unsigned)f2b(a[6] * inv) | ((unsigned)f2b(a[7] * inv) << 16);
        *(uint4*)((char*)Hb + (((unsigned)node << 8) | poff)) = o;
    }
}

// ---------------------------------------------------------------------------
// MFMA GEMM (r4/r7 structure): 128 rows x 128 cols per block, 256 threads =
// 4 waves; wave w -> rows w*32..+31 as 2 row-tiles x 8 col-tiles of 16x16x32.
// W staged in LDS (XOR-swizzled, conflict-free b128); A-fragments stream
// STRAIGHT FROM GLOBAL (fully coalesced, used once). LDS 32 KB.
// ---------------------------------------------------------------------------
template <bool OUT_BF16>
__global__ __launch_bounds__(256) void gemm_mfma(const unsigned short* __restrict__ Hb,
                                                 const unsigned short* __restrict__ Wt,
                                                 const float* __restrict__ b,
                                                 void* __restrict__ outv, int N) {
    __shared__ unsigned short Wa[128 * 128];  // 32 KB
    const int tid = threadIdx.x;
    const int row0 = blockIdx.x * 128;

    // Stage Wa (Wt is [n][k] bf16, 2048 16B chunks, swizzled)
#pragma unroll
    for (int it = 0; it < 8; ++it) {
        int idx = it * 256 + tid;
        int r = idx >> 4, c = idx & 15;
        uint4 v = *(const uint4*)(Wt + r * 128 + c * 8);
        *(uint4*)(Wa + r * 128 + ((c ^ (r & 15)) << 3)) = v;
    }
    __syncthreads();

    const int w = tid >> 6;
    const int lane = tid & 63;
    const int m = lane & 15;   // A row-in-tile / B col-in-tile / C col
    const int q = lane >> 4;   // quad

    // A rows for this lane (clamped; OOB rows never stored)
    const int r0 = row0 + w * 32 + m;
    const size_t ar0 = (size_t)min(r0, N - 1) * 128;
    const size_t ar1 = (size_t)min(r0 + 16, N - 1) * 128;

    f32x4 acc[2][8];
#pragma unroll
    for (int rt = 0; rt < 2; ++rt)
#pragma unroll
        for (int ct = 0; ct < 8; ++ct) acc[rt][ct] = (f32x4){0.f, 0.f, 0.f, 0.f};

#pragma unroll
    for (int kk = 0; kk < 4; ++kk) {
        const int chunk = kk * 4 + q;  // this lane's 16B chunk (8 bf16 of k)
        bf16x8 af0 = *(const bf16x8*)(Hb + ar0 + chunk * 8);
        bf16x8 af1 = *(const bf16x8*)(Hb + ar1 + chunk * 8);
#pragma unroll
        for (int ct = 0; ct < 8; ++ct) {
            int n = ct * 16 + m;
            bf16x8 bfr = *(const bf16x8*)(Wa + n * 128 + ((chunk ^ (n & 15)) << 3));
            acc[0][ct] = __builtin_amdgcn_mfma_f32_16x16x32_bf16(af0, bfr, acc[0][ct], 0, 0, 0);
            acc[1][ct] = __builtin_amdgcn_mfma_f32_16x16x32_bf16(af1, bfr, acc[1][ct], 0, 0, 0);
        }
    }

    // Epilogue: bias + leaky-relu, store (fp32 or bf16)
#pragma unroll
    for (int ct = 0; ct < 8; ++ct) {
        const float bias = b[ct * 16 + m];
        const int gcol = ct * 16 + m;
#pragma unroll
        for (int rt = 0; rt < 2; ++rt) {
#pragma unroll
            for (int reg = 0; reg < 4; ++reg) {
                int grow = row0 + w * 32 + rt * 16 + q * 4 + reg;
                if (grow < N) {
                    float v = acc[rt][ct][reg] + bias;
                    v = v > 0.f ? v : v * NEG_SLOPE;
                    if (OUT_BF16)
                        ((unsigned short*)outv)[(long long)grow * 128 + gcol] = f2b(v);
                    else
                        ((float*)outv)[(long long)grow * 128 + gcol] = v;
                }
            }
        }
    }
}

extern "C" void kernel_launch(void* const* d_in, const int* in_sizes, int n_in,
                              void* d_out, int out_size, void* d_ws, size_t ws_size,
                              hipStream_t stream) {
    const float* feat = (const float*)d_in[0];
    const int*   edges = (const int*)d_in[1];
    const float* W1 = (const float*)d_in[2];
    const float* b1 = (const float*)d_in[3];
    const float* W2 = (const float*)d_in[4];
    const float* b2 = (const float*)d_in[5];
    float* out = (float*)d_out;

    const int N = in_sizes[0] / 128;
    const int E = in_sizes[1] / 2;
    const int* src = edges;
    const int* dst = edges + E;
    const int B = (N + (1 << BSHIFT) - 1) >> BSHIFT;

    // Workspace layout:
    //   featb: N*128 bf16 (x; REUSED as h1 output of gemm1, gather src of agg2)
    //   Hb:    N*128 bf16 (agg output)
    //   Wt1, Wt2, offsets[N], degs[N], bcursor[512], csr[B*CAPB] (packed->sorted)
    unsigned short* featb = (unsigned short*)d_ws;
    unsigned short* Hb    = featb + (size_t)N * 128;
    unsigned short* Wt1   = Hb + (size_t)N * 128;
    unsigned short* Wt2   = Wt1 + 128 * 128;
    int* offsets = (int*)(Wt2 + 128 * 128);
    int* degs    = offsets + ((N + 8) & ~7);
    int* bcursor = degs + ((N + 8) & ~7);
    int* csr     = bcursor + 512;

    const long long nfeat = (long long)N * 128;
    const int nf4 = (int)((nfeat / 4 + 255) / 256);

    front_kernel<<<nf4 + 64, 256, 0, stream>>>(feat, featb, nfeat, W1, W2,
                                               Wt1, Wt2, bcursor, B, nf4);

    {   // cooperative CSR build (bscatter + grid-sync + per-bucket LDS sort)
        const int* srca = src;
        const int* dsta = dst;
        int* bca = bcursor;
        unsigned* csrUa = (unsigned*)csr;
        int* offa = offsets;
        int* dega = degs;
        int Ea = E, Ba = B, Na = N;
        void* kargs[] = {(void*)&srca, (void*)&dsta, (void*)&bca, (void*)&csrUa,
                         (void*)&offa, (void*)&dega, (void*)&Ea, (void*)&Ba,
                         (void*)&Na};
        hipLaunchCooperativeKernel((const void*)csr_build, dim3(B), dim3(256),
                                   kargs, 0, stream);
    }

    const int aggGrid = (N + 3) / 4;
    const int gemmGrid = (N + 127) / 128;

    // Layer 1: gather featb -> Hb; GEMM(W1,b1) -> h1 bf16 into featb
    aggregate_kernel<<<aggGrid, 256, 0, stream>>>(featb, offsets, degs, csr, Hb, N);
    gemm_mfma<true><<<gemmGrid, 256, 0, stream>>>(Hb, Wt1, b1, (void*)featb, N);

    // Layer 2: gather featb(h1) -> Hb; GEMM(W2,b2) -> fp32 out
    aggregate_kernel<<<aggGrid, 256, 0, stream>>>(featb, offsets, degs, csr, Hb, N);
    gemm_mfma<false><<<gemmGrid, 256, 0, stream>>>(Hb, Wt2, b2, (void*)out, N);
}

// Round 9
// 299.087 us; speedup vs baseline: 1.2881x; 1.2881x over previous
//
#include <hip/hip_runtime.h>

#define NEG_SLOPE 0.01f
#define BSHIFT 8          // nodes per dst-bucket = 256
#define BMASK 255
#define BMAX 512          // bucket count bound (supports N <= 131072)
#define CAPB 5120         // static per-bucket capacity (avg 4092, +16 sigma)
#define SCCH 6144         // edges per bscatter block (LDS-staged dst chunk)

typedef __attribute__((ext_vector_type(8))) short bf16x8;
typedef __attribute__((ext_vector_type(4))) float f32x4;
typedef __attribute__((ext_vector_type(2))) float f32x2;
typedef __attribute__((ext_vector_type(4))) unsigned u32x4;

// fp32 -> bf16 (RNE, normals only — fine for this data)
static __device__ inline unsigned short f2b(float f) {
    unsigned u = __builtin_bit_cast(unsigned, f);
    return (unsigned short)((u + 0x7FFF + ((u >> 16) & 1)) >> 16);
}
static __device__ inline float b2f_lo(unsigned u) {
    return __builtin_bit_cast(float, u << 16);
}
static __device__ inline float b2f_hi(unsigned u) {
    return __builtin_bit_cast(float, u & 0xFFFF0000u);
}

// ---------------------------------------------------------------------------
// Front (64 blocks): W1/W2 -> Wt (transposed bf16) + bcursor zeroing.
// (cvt_feat is GONE: gemm1 reads fp32 feat directly.)
// ---------------------------------------------------------------------------
__global__ __launch_bounds__(256) void front_kernel(const float* __restrict__ W1,
                                                    const float* __restrict__ W2,
                                                    unsigned short* __restrict__ Wt1,
                                                    unsigned short* __restrict__ Wt2,
                                                    int* __restrict__ bcursor) {
    int i = blockIdx.x * 256 + threadIdx.x;   // 0..16383
    if (i < BMAX) bcursor[i] = 0;
    int n = i & 127, k = i >> 7;
    Wt1[n * 128 + k] = f2b(W1[k * 128 + n]);
    Wt2[n * 128 + k] = f2b(W2[k * 128 + n]);
}

// ---------------------------------------------------------------------------
// Partition edges into STATIC bucket regions pairs[b*CAPB ..]: per-block LDS
// histogram (dst chunk STAGED IN LDS — read global dst once, not twice) ->
// one global atomicAdd per (block,bucket) reserves a base -> scatter.
// Packed entry: src (24 bits) | local-dst (8 bits).
// ---------------------------------------------------------------------------
__global__ __launch_bounds__(256) void bscatter_kernel(const int* __restrict__ src,
                                                       const int* __restrict__ dst,
                                                       int* __restrict__ bcursor,
                                                       unsigned* __restrict__ pairs,
                                                       int E, int B) {
    __shared__ int h[BMAX];
    __shared__ int base[BMAX];
    __shared__ int dl[SCCH];                  // 24 KB staged dst chunk
    const int t = threadIdx.x;
    for (int i = t; i < B; i += 256) h[i] = 0;
    __syncthreads();
    const int e0 = blockIdx.x * SCCH;
    const int e1 = min(e0 + SCCH, E);
    for (int e = e0 + t; e < e1; e += 256) {
        int d = dst[e];
        dl[e - e0] = d;
        atomicAdd(&h[d >> BSHIFT], 1);
    }
    __syncthreads();
    for (int i = t; i < B; i += 256) {
        int c = h[i];
        base[i] = c ? atomicAdd(&bcursor[i], c) : 0;
    }
    __syncthreads();
    for (int i = t; i < B; i += 256) h[i] = base[i];
    __syncthreads();
    for (int e = e0 + t; e < e1; e += 256) {
        int d = dl[e - e0];
        int bb = d >> BSHIFT;
        int pos = atomicAdd(&h[bb], 1);
        if (pos < CAPB)
            pairs[(size_t)bb * CAPB + pos] = (unsigned)src[e] | ((unsigned)(d & BMASK) << 24);
    }
}

// ---------------------------------------------------------------------------
// Per-bucket finalize: LDS histogram of 256 local dsts -> scan -> per-node
// offsets (absolute into static csr region) + degs + scatter src into csr.
// ---------------------------------------------------------------------------
__global__ __launch_bounds__(256) void bfinal_kernel(const unsigned* __restrict__ pairs,
                                                     const int* __restrict__ bcursor,
                                                     int* __restrict__ offsets,
                                                     int* __restrict__ degs,
                                                     int* __restrict__ csr, int N) {
    __shared__ int h[256];
    __shared__ int cur[256];
    const int b = blockIdx.x;
    const int t = threadIdx.x;
    const int cnt = min(bcursor[b], CAPB);
    const unsigned* __restrict__ pb = pairs + (size_t)b * CAPB;
    h[t] = 0;
    __syncthreads();
    for (int e = t; e < cnt; e += 256)
        atomicAdd(&h[pb[e] >> 24], 1);
    __syncthreads();
    int v = h[t];
    for (int d = 1; d < 256; d <<= 1) {
        int u = (t >= d) ? h[t - d] : 0;
        __syncthreads();
        h[t] += u;
        __syncthreads();
    }
    const int prefix = h[t] - v;          // exclusive prefix within bucket
    const int node = (b << BSHIFT) + t;
    if (node < N) {
        offsets[node] = b * CAPB + prefix;
        degs[node] = v;
    }
    cur[t] = prefix;
    __syncthreads();
    int* __restrict__ cb = csr + (size_t)b * CAPB;
    for (int e = t; e < cnt; e += 256) {
        unsigned pr = pb[e];
        int pos = atomicAdd(&cur[pr >> 24], 1);
        cb[pos] = (int)(pr & 0xFFFFFFu);
    }
}

// ---------------------------------------------------------------------------
// GEMM-first layer (aggregation commutes with the linear map):
//   y = in @ W  (no bias/activation — applied post-aggregation).
// 128 rows x 128 cols per block, 4 waves; W staged in LDS (XOR-swizzled);
// A-fragments stream straight from global (fp32 input casts in-register).
// ---------------------------------------------------------------------------
template <bool IN_F32>
__global__ __launch_bounds__(256) void gemm_xw(const void* __restrict__ inA,
                                               const unsigned short* __restrict__ Wt,
                                               unsigned short* __restrict__ outy,
                                               int N) {
    __shared__ unsigned short Wa[128 * 128];  // 32 KB
    const int tid = threadIdx.x;
    const int row0 = blockIdx.x * 128;

#pragma unroll
    for (int it = 0; it < 8; ++it) {
        int idx = it * 256 + tid;
        int r = idx >> 4, c = idx & 15;
        uint4 v = *(const uint4*)(Wt + r * 128 + c * 8);
        *(uint4*)(Wa + r * 128 + ((c ^ (r & 15)) << 3)) = v;
    }
    __syncthreads();

    const int w = tid >> 6;
    const int lane = tid & 63;
    const int m = lane & 15;
    const int q = lane >> 4;

    const int r0 = row0 + w * 32 + m;
    const size_t ar0 = (size_t)min(r0, N - 1) * 128;
    const size_t ar1 = (size_t)min(r0 + 16, N - 1) * 128;

    f32x4 acc[2][8];
#pragma unroll
    for (int rt = 0; rt < 2; ++rt)
#pragma unroll
        for (int ct = 0; ct < 8; ++ct) acc[rt][ct] = (f32x4){0.f, 0.f, 0.f, 0.f};

#pragma unroll
    for (int kk = 0; kk < 4; ++kk) {
        const int chunk = kk * 4 + q;
        bf16x8 af0, af1;
        if (IN_F32) {
            const float* Af = (const float*)inA;
            float4 u0 = *(const float4*)(Af + ar0 + chunk * 8);
            float4 u1 = *(const float4*)(Af + ar0 + chunk * 8 + 4);
            float4 u2 = *(const float4*)(Af + ar1 + chunk * 8);
            float4 u3 = *(const float4*)(Af + ar1 + chunk * 8 + 4);
            af0[0] = (short)f2b(u0.x); af0[1] = (short)f2b(u0.y);
            af0[2] = (short)f2b(u0.z); af0[3] = (short)f2b(u0.w);
            af0[4] = (short)f2b(u1.x); af0[5] = (short)f2b(u1.y);
            af0[6] = (short)f2b(u1.z); af0[7] = (short)f2b(u1.w);
            af1[0] = (short)f2b(u2.x); af1[1] = (short)f2b(u2.y);
            af1[2] = (short)f2b(u2.z); af1[3] = (short)f2b(u2.w);
            af1[4] = (short)f2b(u3.x); af1[5] = (short)f2b(u3.y);
            af1[6] = (short)f2b(u3.z); af1[7] = (short)f2b(u3.w);
        } else {
            const unsigned short* Ab = (const unsigned short*)inA;
            af0 = *(const bf16x8*)(Ab + ar0 + chunk * 8);
            af1 = *(const bf16x8*)(Ab + ar1 + chunk * 8);
        }
#pragma unroll
        for (int ct = 0; ct < 8; ++ct) {
            int n = ct * 16 + m;
            bf16x8 bfr = *(const bf16x8*)(Wa + n * 128 + ((chunk ^ (n & 15)) << 3));
            acc[0][ct] = __builtin_amdgcn_mfma_f32_16x16x32_bf16(af0, bfr, acc[0][ct], 0, 0, 0);
            acc[1][ct] = __builtin_amdgcn_mfma_f32_16x16x32_bf16(af1, bfr, acc[1][ct], 0, 0, 0);
        }
    }

    // store raw y (bf16), no bias/activation
#pragma unroll
    for (int ct = 0; ct < 8; ++ct) {
        const int gcol = ct * 16 + m;
#pragma unroll
        for (int rt = 0; rt < 2; ++rt) {
#pragma unroll
            for (int reg = 0; reg < 4; ++reg) {
                int grow = row0 + w * 32 + rt * 16 + q * 4 + reg;
                if (grow < N)
                    outy[(long long)grow * 128 + gcol] = f2b(acc[rt][ct][reg]);
            }
        }
    }
}

// ---------------------------------------------------------------------------
// Aggregate + epilogue (r5/r7 gather structure — proven ~60 us): one wave
// per node; 4 lane-groups of 16; scalar-path indices; exact-count inline-asm
// gathers, 4 KB in flight. Epilogue applies /(deg+1) + bias + leaky-relu
// (valid because aggregation commutes with the weight multiply) and writes
// the LAYER OUTPUT directly (bf16 h1 or fp32 out) — no Hb intermediate.
// ---------------------------------------------------------------------------
static __device__ inline f32x2 up2(unsigned u) {
    return (f32x2){ b2f_lo(u), b2f_hi(u) };
}

#define GATHER(dst, off) \
    asm volatile("global_load_dwordx4 %0, %1, %2" : "=v"(dst) : "v"(off), "s"(xc))
#define ACC4(u) do { A0 += up2((u).x); A1 += up2((u).y); \
                     A2 += up2((u).z); A3 += up2((u).w); } while (0)
#define ACCM(u, mk) do { \
    A0 += up2((u).x & (mk)); A1 += up2((u).y & (mk)); \
    A2 += up2((u).z & (mk)); A3 += up2((u).w & (mk)); } while (0)

static __device__ __forceinline__ unsigned rowsel(int g, unsigned poff,
                                                  int i0, int i1, int i2, int i3) {
    int s01 = (g & 1) ? i1 : i0;
    int s23 = (g & 1) ? i3 : i2;
    int s = (g & 2) ? s23 : s01;
    return ((unsigned)s << 8) | poff;
}

template <bool OUT_F32>
__global__ __launch_bounds__(256) void agg_apply(const unsigned short* __restrict__ xb,
                                                 const int* __restrict__ offsets,
                                                 const int* __restrict__ degs,
                                                 const int* __restrict__ csr,
                                                 const float* __restrict__ bias,
                                                 void* __restrict__ outv, int N) {
    const int node = (blockIdx.x * blockDim.x + threadIdx.x) >> 6;
    if (node >= N) return;
    const int lane = threadIdx.x & 63;
    const int g = lane >> 4;                              // neighbor slot 0..3
    const unsigned poff = (unsigned)((lane & 15) << 4);   // 16B chunk in row
    const char* __restrict__ xc = (const char*)xb;

    // wave-uniform node -> scalar offsets/degs/csr loads (SMEM path)
    const int nu = __builtin_amdgcn_readfirstlane(node);
    const int start = __builtin_amdgcn_readfirstlane(offsets[nu]);
    const int deg   = __builtin_amdgcn_readfirstlane(degs[nu]);
    const int rounds = deg >> 2;
    const int tailn  = deg & 3;

    // self gather: group 0 only; consumed post-reduce
    u32x4 vs = (u32x4){0, 0, 0, 0};
    if (g == 0) GATHER(vs, ((unsigned)nu << 8) | poff);

    f32x2 A0 = {0.f, 0.f}, A1 = {0.f, 0.f}, A2 = {0.f, 0.f}, A3 = {0.f, 0.f};

    int r = 0;
    while (r + 4 <= rounds) {             // wave-uniform
        const int p = start + (r << 2);
        int i0  = csr[p +  0], i1  = csr[p +  1], i2  = csr[p +  2], i3  = csr[p +  3];
        int i4  = csr[p +  4], i5  = csr[p +  5], i6  = csr[p +  6], i7  = csr[p +  7];
        int i8  = csr[p +  8], i9  = csr[p +  9], i10 = csr[p + 10], i11 = csr[p + 11];
        int i12 = csr[p + 12], i13 = csr[p + 13], i14 = csr[p + 14], i15 = csr[p + 15];
        unsigned a0 = rowsel(g, poff, i0,  i1,  i2,  i3);
        unsigned a1 = rowsel(g, poff, i4,  i5,  i6,  i7);
        unsigned a2 = rowsel(g, poff, i8,  i9,  i10, i11);
        unsigned a3 = rowsel(g, poff, i12, i13, i14, i15);
        __builtin_amdgcn_sched_barrier(0);
        u32x4 v0, v1, v2, v3;
        GATHER(v0, a0); GATHER(v1, a1); GATHER(v2, a2); GATHER(v3, a3);
        asm volatile("s_waitcnt vmcnt(0)" ::: "memory");
        __builtin_amdgcn_sched_barrier(0);
        ACC4(v0); ACC4(v1); ACC4(v2); ACC4(v3);
        r += 4;
    }

    // remainder rounds (0..3) + tail, exact counts, wave-uniform branches
    const int rr = rounds - r;
    const int p = start + (r << 2);
    u32x4 v0, v1, v2, vt;
    if (rr >= 1) {
        int i0 = csr[p + 0], i1 = csr[p + 1], i2 = csr[p + 2], i3 = csr[p + 3];
        GATHER(v0, rowsel(g, poff, i0, i1, i2, i3));
    }
    if (rr >= 2) {
        int i0 = csr[p + 4], i1 = csr[p + 5], i2 = csr[p + 6], i3 = csr[p + 7];
        GATHER(v1, rowsel(g, poff, i0, i1, i2, i3));
    }
    if (rr >= 3) {
        int i0 = csr[p + 8], i1 = csr[p + 9], i2 = csr[p + 10], i3 = csr[p + 11];
        GATHER(v2, rowsel(g, poff, i0, i1, i2, i3));
    }
    const unsigned mt = (g < tailn) ? ~0u : 0u;
    if (tailn) {
        const int q = start + (rounds << 2);
        int t0 = csr[q];
        int t1 = (tailn > 1) ? csr[q + 1] : t0;
        int t2 = (tailn > 2) ? csr[q + 2] : t0;
        GATHER(vt, rowsel(g, poff, t0, t1, t2, t0));
    }
    asm volatile("s_waitcnt vmcnt(0)" ::: "memory");
    __builtin_amdgcn_sched_barrier(0);
    if (rr >= 1) ACC4(v0);
    if (rr >= 2) ACC4(v1);
    if (rr >= 3) ACC4(v2);
    if (tailn) ACCM(vt, mt);

    // combine the 4 lane-groups: butterfly leaves full sum in every lane
    float a[8];
    a[0] = A0.x; a[1] = A0.y; a[2] = A1.x; a[3] = A1.y;
    a[4] = A2.x; a[5] = A2.y; a[6] = A3.x; a[7] = A3.y;
#pragma unroll
    for (int i = 0; i < 8; ++i) {
        a[i] += __shfl_xor(a[i], 16);
        a[i] += __shfl_xor(a[i], 32);
    }
    // self term (group 0 only holds it; group 0 is the storing group)
    a[0] += b2f_lo(vs.x); a[1] += b2f_hi(vs.x);
    a[2] += b2f_lo(vs.y); a[3] += b2f_hi(vs.y);
    a[4] += b2f_lo(vs.z); a[5] += b2f_hi(vs.z);
    a[6] += b2f_lo(vs.w); a[7] += b2f_hi(vs.w);

    const float inv = 1.0f / (float)(deg + 1);
    if (g == 0) {
        const int c0 = (lane & 15) << 3;
        const float4 bb0 = *(const float4*)(bias + c0);
        const float4 bb1 = *(const float4*)(bias + c0 + 4);
        float rv[8];
        rv[0] = a[0] * inv + bb0.x; rv[1] = a[1] * inv + bb0.y;
        rv[2] = a[2] * inv + bb0.z; rv[3] = a[3] * inv + bb0.w;
        rv[4] = a[4] * inv + bb1.x; rv[5] = a[5] * inv + bb1.y;
        rv[6] = a[6] * inv + bb1.z; rv[7] = a[7] * inv + bb1.w;
#pragma unroll
        for (int k = 0; k < 8; ++k) rv[k] = rv[k] > 0.f ? rv[k] : rv[k] * NEG_SLOPE;
        if (OUT_F32) {
            float* op = (float*)outv + (size_t)node * 128 + c0;
            *(float4*)op = make_float4(rv[0], rv[1], rv[2], rv[3]);
            *(float4*)(op + 4) = make_float4(rv[4], rv[5], rv[6], rv[7]);
        } else {
            uint4 o;
            o.x = (unsigned)f2b(rv[0]) | ((unsigned)f2b(rv[1]) << 16);
            o.y = (unsigned)f2b(rv[2]) | ((unsigned)f2b(rv[3]) << 16);
            o.z = (unsigned)f2b(rv[4]) | ((unsigned)f2b(rv[5]) << 16);
            o.w = (unsigned)f2b(rv[6]) | ((unsigned)f2b(rv[7]) << 16);
            *(uint4*)((char*)outv + (((unsigned)node << 8) | poff)) = o;
        }
    }
}

extern "C" void kernel_launch(void* const* d_in, const int* in_sizes, int n_in,
                              void* d_out, int out_size, void* d_ws, size_t ws_size,
                              hipStream_t stream) {
    const float* feat = (const float*)d_in[0];
    const int*   edges = (const int*)d_in[1];
    const float* W1 = (const float*)d_in[2];
    const float* b1 = (const float*)d_in[3];
    const float* W2 = (const float*)d_in[4];
    const float* b2 = (const float*)d_in[5];
    float* out = (float*)d_out;

    const int N = in_sizes[0] / 128;
    const int E = in_sizes[1] / 2;
    const int* src = edges;
    const int* dst = edges + E;
    const int B = (N + (1 << BSHIFT) - 1) >> BSHIFT;

    // Workspace:
    //   T1: N*128 bf16 (y1 = feat@W1; later y2 = h1@W2)
    //   T2: N*128 bf16 (pairs alias during CSR build; then h1)
    //   Wt1, Wt2, offsets[N], degs[N], bcursor[512], csr[B*CAPB]
    unsigned short* T1  = (unsigned short*)d_ws;
    unsigned short* T2  = T1 + (size_t)N * 128;
    unsigned*       pairs = (unsigned*)T2;
    unsigned short* Wt1 = T2 + (size_t)N * 128;
    unsigned short* Wt2 = Wt1 + 128 * 128;
    int* offsets = (int*)(Wt2 + 128 * 128);
    int* degs    = offsets + ((N + 8) & ~7);
    int* bcursor = degs + ((N + 8) & ~7);
    int* csr     = bcursor + 512;

    const int gemmGrid = (N + 127) / 128;
    const int aggGrid  = (N + 3) / 4;
    const int scGrid   = (E + SCCH - 1) / SCCH;

    // Wt + bcursor zero
    front_kernel<<<64, 256, 0, stream>>>(W1, W2, Wt1, Wt2, bcursor);
    // y1 = feat(fp32) @ W1  (independent of CSR build)
    gemm_xw<true><<<gemmGrid, 256, 0, stream>>>(feat, Wt1, T1, N);
    // CSR build
    bscatter_kernel<<<scGrid, 256, 0, stream>>>(src, dst, bcursor, pairs, E, B);
    bfinal_kernel<<<B, 256, 0, stream>>>(pairs, bcursor, offsets, degs, csr, N);
    // h1 = leaky(L(y1) + b1)  (bf16, overwrites pairs region)
    agg_apply<false><<<aggGrid, 256, 0, stream>>>(T1, offsets, degs, csr, b1,
                                                  (void*)T2, N);
    // y2 = h1 @ W2
    gemm_xw<false><<<gemmGrid, 256, 0, stream>>>(T2, Wt2, T1, N);
    // out = leaky(L(y2) + b2)  (fp32)
    agg_apply<true><<<aggGrid, 256, 0, stream>>>(T1, offsets, degs, csr, b2,
                                                 (void*)out, N);
}

// Round 11
// 277.717 us; speedup vs baseline: 1.3872x; 1.0769x over previous
//
#include <hip/hip_runtime.h>

#define NEG_SLOPE 0.01f
#define BSHIFT 8          // nodes per dst-bucket = 256
#define BMASK 255
#define BMAX 512          // bucket count bound (supports N <= 131072)
#define CAPB 5120         // static per-bucket capacity (avg 4092, +16 sigma)
#define SCCH 4096         // edges per bscatter block (4/thread @ 1024 threads)

typedef __attribute__((ext_vector_type(8))) short bf16x8;
typedef __attribute__((ext_vector_type(4))) float f32x4;
typedef __attribute__((ext_vector_type(2))) float f32x2;
typedef __attribute__((ext_vector_type(4))) unsigned u32x4;

// fp32 -> bf16 (RNE, normals only — fine for this data)
static __device__ inline unsigned short f2b(float f) {
    unsigned u = __builtin_bit_cast(unsigned, f);
    return (unsigned short)((u + 0x7FFF + ((u >> 16) & 1)) >> 16);
}
static __device__ inline float b2f_lo(unsigned u) {
    return __builtin_bit_cast(float, u << 16);
}
static __device__ inline float b2f_hi(unsigned u) {
    return __builtin_bit_cast(float, u & 0xFFFF0000u);
}

// ---------------------------------------------------------------------------
// bscatter (1024 threads, 32 waves/CU — r9 ran 4 waves/CU and was latency-
// starved): 4 edges/thread held in REGISTERS (int4 loads, no LDS staging;
// LDS = 4 KB histogram only). Per-block LDS histogram -> one global atomicAdd
// per (block,bucket) -> scatter packed (src 24b | local-dst 8b) into static
// bucket regions. Tail blocks [scGrid, scGrid+16) do the W1/W2 transpose to
// bf16 (front_kernel folded in; bcursor zeroing moved to hipMemsetAsync).
// ---------------------------------------------------------------------------
__global__ __launch_bounds__(1024) void bscatter_kernel(const int* __restrict__ src,
                                                        const int* __restrict__ dst,
                                                        int* __restrict__ bcursor,
                                                        unsigned* __restrict__ pairs,
                                                        const float* __restrict__ W1,
                                                        const float* __restrict__ W2,
                                                        unsigned short* __restrict__ Wt1,
                                                        unsigned short* __restrict__ Wt2,
                                                        int E, int B, int scGrid) {
    const int bx = blockIdx.x;
    const int t = threadIdx.x;
    if (bx >= scGrid) {                    // W transpose tail (16 blocks)
        int i = (bx - scGrid) * 1024 + t;  // 0..16383
        int n = i & 127, k = i >> 7;
        Wt1[n * 128 + k] = f2b(W1[k * 128 + n]);
        Wt2[n * 128 + k] = f2b(W2[k * 128 + n]);
        return;
    }
    __shared__ int h[BMAX];
    __shared__ int base[BMAX];
    for (int i = t; i < B; i += 1024) h[i] = 0;
    __syncthreads();
    const int e0 = bx * SCCH;
    const int e1 = min(e0 + SCCH, E);
    const int idx = e0 + t * 4;
    const int nv = min(max(e1 - idx, 0), 4);
    int d0 = 0, d1 = 0, d2 = 0, d3 = 0, s0 = 0, s1 = 0, s2 = 0, s3 = 0;
    if (nv == 4) {
        int4 d4 = *(const int4*)(dst + idx);
        int4 s4 = *(const int4*)(src + idx);
        d0 = d4.x; d1 = d4.y; d2 = d4.z; d3 = d4.w;
        s0 = s4.x; s1 = s4.y; s2 = s4.z; s3 = s4.w;
    } else if (nv > 0) {
        d0 = dst[idx]; s0 = src[idx];
        if (nv > 1) { d1 = dst[idx + 1]; s1 = src[idx + 1]; }
        if (nv > 2) { d2 = dst[idx + 2]; s2 = src[idx + 2]; }
    }
    if (nv > 0) atomicAdd(&h[d0 >> BSHIFT], 1);
    if (nv > 1) atomicAdd(&h[d1 >> BSHIFT], 1);
    if (nv > 2) atomicAdd(&h[d2 >> BSHIFT], 1);
    if (nv > 3) atomicAdd(&h[d3 >> BSHIFT], 1);
    __syncthreads();
    for (int i = t; i < B; i += 1024) {
        int c = h[i];
        base[i] = c ? atomicAdd(&bcursor[i], c) : 0;
    }
    __syncthreads();
    for (int i = t; i < B; i += 1024) h[i] = base[i];
    __syncthreads();
#define SCAT(dd, ss) do { int bb = (dd) >> BSHIFT; int pos = atomicAdd(&h[bb], 1); \
    if (pos < CAPB) pairs[(size_t)bb * CAPB + pos] = \
        (unsigned)(ss) | ((unsigned)((dd) & BMASK) << 24); } while (0)
    if (nv > 0) SCAT(d0, s0);
    if (nv > 1) SCAT(d1, s1);
    if (nv > 2) SCAT(d2, s2);
    if (nv > 3) SCAT(d3, s3);
#undef SCAT
}

// ---------------------------------------------------------------------------
// bfinal (1024 threads): stage bucket in LDS ONCE (pairs read once, not
// twice), histogram -> scan -> LDS counting-sort scatter -> COALESCED csr
// write-back. Writes per-node offsets (absolute into static region) + degs.
// LDS 42 KB; ~3 blocks/CU co-residency at 16 waves each.
// ---------------------------------------------------------------------------
__global__ __launch_bounds__(1024) void bfinal_kernel(const unsigned* __restrict__ pairs,
                                                      const int* __restrict__ bcursor,
                                                      int* __restrict__ offsets,
                                                      int* __restrict__ degs,
                                                      int* __restrict__ csr, int N) {
    __shared__ unsigned stage[CAPB];     // 20 KB
    __shared__ unsigned sorted[CAPB];    // 20 KB
    __shared__ int h[256];
    __shared__ int cur[256];
    const int b = blockIdx.x;
    const int t = threadIdx.x;
    const int cnt = min(bcursor[b], CAPB);
    const unsigned* __restrict__ pb = pairs + (size_t)b * CAPB;
    if (t < 256) h[t] = 0;
    for (int e = t; e < cnt; e += 1024) stage[e] = pb[e];
    __syncthreads();
    for (int e = t; e < cnt; e += 1024)
        atomicAdd(&h[stage[e] >> 24], 1);
    __syncthreads();
    int v = (t < 256) ? h[t] : 0;
    for (int d = 1; d < 256; d <<= 1) {
        int u = (t < 256 && t >= d) ? h[t - d] : 0;
        __syncthreads();
        if (t < 256) h[t] += u;
        __syncthreads();
    }
    if (t < 256) {
        const int prefix = h[t] - v;      // exclusive prefix within bucket
        const int node = (b << BSHIFT) + t;
        if (node < N) {
            offsets[node] = b * CAPB + prefix;
            degs[node] = v;
        }
        cur[t] = prefix;
    }
    __syncthreads();
    for (int e = t; e < cnt; e += 1024) {
        unsigned pr = stage[e];
        int pos = atomicAdd(&cur[pr >> 24], 1);
        sorted[pos] = pr & 0xFFFFFFu;
    }
    __syncthreads();
    int* __restrict__ cb = csr + (size_t)b * CAPB;
    for (int e = t; e < cnt; e += 1024) cb[e] = (int)sorted[e];   // coalesced
}

// ---------------------------------------------------------------------------
// GEMM-first layer (aggregation commutes with the linear map):
//   y = in @ W  (no bias/activation — applied post-aggregation).
// 128 rows x 128 cols per block, 4 waves; W staged in LDS (XOR-swizzled);
// A-fragments stream straight from global (fp32 input casts in-register).
// ---------------------------------------------------------------------------
template <bool IN_F32>
__global__ __launch_bounds__(256) void gemm_xw(const void* __restrict__ inA,
                                               const unsigned short* __restrict__ Wt,
                                               unsigned short* __restrict__ outy,
                                               int N) {
    __shared__ unsigned short Wa[128 * 128];  // 32 KB
    const int tid = threadIdx.x;
    const int row0 = blockIdx.x * 128;

#pragma unroll
    for (int it = 0; it < 8; ++it) {
        int idx = it * 256 + tid;
        int r = idx >> 4, c = idx & 15;
        uint4 v = *(const uint4*)(Wt + r * 128 + c * 8);
        *(uint4*)(Wa + r * 128 + ((c ^ (r & 15)) << 3)) = v;
    }
    __syncthreads();

    const int w = tid >> 6;
    const int lane = tid & 63;
    const int m = lane & 15;
    const int q = lane >> 4;

    const int r0 = row0 + w * 32 + m;
    const size_t ar0 = (size_t)min(r0, N - 1) * 128;
    const size_t ar1 = (size_t)min(r0 + 16, N - 1) * 128;

    f32x4 acc[2][8];
#pragma unroll
    for (int rt = 0; rt < 2; ++rt)
#pragma unroll
        for (int ct = 0; ct < 8; ++ct) acc[rt][ct] = (f32x4){0.f, 0.f, 0.f, 0.f};

#pragma unroll
    for (int kk = 0; kk < 4; ++kk) {
        const int chunk = kk * 4 + q;
        bf16x8 af0, af1;
        if (IN_F32) {
            const float* Af = (const float*)inA;
            float4 u0 = *(const float4*)(Af + ar0 + chunk * 8);
            float4 u1 = *(const float4*)(Af + ar0 + chunk * 8 + 4);
            float4 u2 = *(const float4*)(Af + ar1 + chunk * 8);
            float4 u3 = *(const float4*)(Af + ar1 + chunk * 8 + 4);
            af0[0] = (short)f2b(u0.x); af0[1] = (short)f2b(u0.y);
            af0[2] = (short)f2b(u0.z); af0[3] = (short)f2b(u0.w);
            af0[4] = (short)f2b(u1.x); af0[5] = (short)f2b(u1.y);
            af0[6] = (short)f2b(u1.z); af0[7] = (short)f2b(u1.w);
            af1[0] = (short)f2b(u2.x); af1[1] = (short)f2b(u2.y);
            af1[2] = (short)f2b(u2.z); af1[3] = (short)f2b(u2.w);
            af1[4] = (short)f2b(u3.x); af1[5] = (short)f2b(u3.y);
            af1[6] = (short)f2b(u3.z); af1[7] = (short)f2b(u3.w);
        } else {
            const unsigned short* Ab = (const unsigned short*)inA;
            af0 = *(const bf16x8*)(Ab + ar0 + chunk * 8);
            af1 = *(const bf16x8*)(Ab + ar1 + chunk * 8);
        }
#pragma unroll
        for (int ct = 0; ct < 8; ++ct) {
            int n = ct * 16 + m;
            bf16x8 bfr = *(const bf16x8*)(Wa + n * 128 + ((chunk ^ (n & 15)) << 3));
            acc[0][ct] = __builtin_amdgcn_mfma_f32_16x16x32_bf16(af0, bfr, acc[0][ct], 0, 0, 0);
            acc[1][ct] = __builtin_amdgcn_mfma_f32_16x16x32_bf16(af1, bfr, acc[1][ct], 0, 0, 0);
        }
    }

    // store raw y (bf16), no bias/activation
#pragma unroll
    for (int ct = 0; ct < 8; ++ct) {
        const int gcol = ct * 16 + m;
#pragma unroll
        for (int rt = 0; rt < 2; ++rt) {
#pragma unroll
            for (int reg = 0; reg < 4; ++reg) {
                int grow = row0 + w * 32 + rt * 16 + q * 4 + reg;
                if (grow < N)
                    outy[(long long)grow * 128 + gcol] = f2b(acc[rt][ct][reg]);
            }
        }
    }
}

// ---------------------------------------------------------------------------
// Aggregate + epilogue (r5/r7 gather structure — proven plateau ~60-64 us;
// FROZEN): one wave per node; 4 lane-groups of 16; scalar-path indices;
// exact-count inline-asm gathers, 4 KB in flight. Epilogue applies /(deg+1)
// + bias + leaky-relu and writes the layer output directly.
// ---------------------------------------------------------------------------
static __device__ inline f32x2 up2(unsigned u) {
    return (f32x2){ b2f_lo(u), b2f_hi(u) };
}

#define GATHER(dst, off) \
    asm volatile("global_load_dwordx4 %0, %1, %2" : "=v"(dst) : "v"(off), "s"(xc))
#define ACC4(u) do { A0 += up2((u).x); A1 += up2((u).y); \
                     A2 += up2((u).z); A3 += up2((u).w); } while (0)
#define ACCM(u, mk) do { \
    A0 += up2((u).x & (mk)); A1 += up2((u).y & (mk)); \
    A2 += up2((u).z & (mk)); A3 += up2((u).w & (mk)); } while (0)

static __device__ __forceinline__ unsigned rowsel(int g, unsigned poff,
                                                  int i0, int i1, int i2, int i3) {
    int s01 = (g & 1) ? i1 : i0;
    int s23 = (g & 1) ? i3 : i2;
    int s = (g & 2) ? s23 : s01;
    return ((unsigned)s << 8) | poff;
}

template <bool OUT_F32>
__global__ __launch_bounds__(256) void agg_apply(const unsigned short* __restrict__ xb,
                                                 const int* __restrict__ offsets,
                                                 const int* __restrict__ degs,
                                                 const int* __restrict__ csr,
                                                 const float* __restrict__ bias,
                                                 void* __restrict__ outv, int N) {
    const int node = (blockIdx.x * blockDim.x + threadIdx.x) >> 6;
    if (node >= N) return;
    const int lane = threadIdx.x & 63;
    const int g = lane >> 4;                              // neighbor slot 0..3
    const unsigned poff = (unsigned)((lane & 15) << 4);   // 16B chunk in row
    const char* __restrict__ xc = (const char*)xb;

    // wave-uniform node -> scalar offsets/degs/csr loads (SMEM path)
    const int nu = __builtin_amdgcn_readfirstlane(node);
    const int start = __builtin_amdgcn_readfirstlane(offsets[nu]);
    const int deg   = __builtin_amdgcn_readfirstlane(degs[nu]);
    const int rounds = deg >> 2;
    const int tailn  = deg & 3;

    // self gather: group 0 only; consumed post-reduce
    u32x4 vs = (u32x4){0, 0, 0, 0};
    if (g == 0) GATHER(vs, ((unsigned)nu << 8) | poff);

    f32x2 A0 = {0.f, 0.f}, A1 = {0.f, 0.f}, A2 = {0.f, 0.f}, A3 = {0.f, 0.f};

    int r = 0;
    while (r + 4 <= rounds) {             // wave-uniform
        const int p = start + (r << 2);
        int i0  = csr[p +  0], i1  = csr[p +  1], i2  = csr[p +  2], i3  = csr[p +  3];
        int i4  = csr[p +  4], i5  = csr[p +  5], i6  = csr[p +  6], i7  = csr[p +  7];
        int i8  = csr[p +  8], i9  = csr[p +  9], i10 = csr[p + 10], i11 = csr[p + 11];
        int i12 = csr[p + 12], i13 = csr[p + 13], i14 = csr[p + 14], i15 = csr[p + 15];
        unsigned a0 = rowsel(g, poff, i0,  i1,  i2,  i3);
        unsigned a1 = rowsel(g, poff, i4,  i5,  i6,  i7);
        unsigned a2 = rowsel(g, poff, i8,  i9,  i10, i11);
        unsigned a3 = rowsel(g, poff, i12, i13, i14, i15);
        __builtin_amdgcn_sched_barrier(0);
        u32x4 v0, v1, v2, v3;
        GATHER(v0, a0); GATHER(v1, a1); GATHER(v2, a2); GATHER(v3, a3);
        asm volatile("s_waitcnt vmcnt(0)" ::: "memory");
        __builtin_amdgcn_sched_barrier(0);
        ACC4(v0); ACC4(v1); ACC4(v2); ACC4(v3);
        r += 4;
    }

    // remainder rounds (0..3) + tail, exact counts, wave-uniform branches
    const int rr = rounds - r;
    const int p = start + (r << 2);
    u32x4 v0, v1, v2, vt;
    if (rr >= 1) {
        int i0 = csr[p + 0], i1 = csr[p + 1], i2 = csr[p + 2], i3 = csr[p + 3];
        GATHER(v0, rowsel(g, poff, i0, i1, i2, i3));
    }
    if (rr >= 2) {
        int i0 = csr[p + 4], i1 = csr[p + 5], i2 = csr[p + 6], i3 = csr[p + 7];
        GATHER(v1, rowsel(g, poff, i0, i1, i2, i3));
    }
    if (rr >= 3) {
        int i0 = csr[p + 8], i1 = csr[p + 9], i2 = csr[p + 10], i3 = csr[p + 11];
        GATHER(v2, rowsel(g, poff, i0, i1, i2, i3));
    }
    const unsigned mt = (g < tailn) ? ~0u : 0u;
    if (tailn) {
        const int q = start + (rounds << 2);
        int t0 = csr[q];
        int t1 = (tailn > 1) ? csr[q + 1] : t0;
        int t2 = (tailn > 2) ? csr[q + 2] : t0;
        GATHER(vt, rowsel(g, poff, t0, t1, t2, t0));
    }
    asm volatile("s_waitcnt vmcnt(0)" ::: "memory");
    __builtin_amdgcn_sched_barrier(0);
    if (rr >= 1) ACC4(v0);
    if (rr >= 2) ACC4(v1);
    if (rr >= 3) ACC4(v2);
    if (tailn) ACCM(vt, mt);

    // combine the 4 lane-groups: butterfly leaves full sum in every lane
    float a[8];
    a[0] = A0.x; a[1] = A0.y; a[2] = A1.x; a[3] = A1.y;
    a[4] = A2.x; a[5] = A2.y; a[6] = A3.x; a[7] = A3.y;
#pragma unroll
    for (int i = 0; i < 8; ++i) {
        a[i] += __shfl_xor(a[i], 16);
        a[i] += __shfl_xor(a[i], 32);
    }
    // self term (group 0 only holds it; group 0 is the storing group)
    a[0] += b2f_lo(vs.x); a[1] += b2f_hi(vs.x);
    a[2] += b2f_lo(vs.y); a[3] += b2f_hi(vs.y);
    a[4] += b2f_lo(vs.z); a[5] += b2f_hi(vs.z);
    a[6] += b2f_lo(vs.w); a[7] += b2f_hi(vs.w);

    const float inv = 1.0f / (float)(deg + 1);
    if (g == 0) {
        const int c0 = (lane & 15) << 3;
        const float4 bb0 = *(const float4*)(bias + c0);
        const float4 bb1 = *(const float4*)(bias + c0 + 4);
        float rv[8];
        rv[0] = a[0] * inv + bb0.x; rv[1] = a[1] * inv + bb0.y;
        rv[2] = a[2] * inv + bb0.z; rv[3] = a[3] * inv + bb0.w;
        rv[4] = a[4] * inv + bb1.x; rv[5] = a[5] * inv + bb1.y;
        rv[6] = a[6] * inv + bb1.z; rv[7] = a[7] * inv + bb1.w;
#pragma unroll
        for (int k = 0; k < 8; ++k) rv[k] = rv[k] > 0.f ? rv[k] : rv[k] * NEG_SLOPE;
        if (OUT_F32) {
            float* op = (float*)outv + (size_t)node * 128 + c0;
            *(float4*)op = make_float4(rv[0], rv[1], rv[2], rv[3]);
            *(float4*)(op + 4) = make_float4(rv[4], rv[5], rv[6], rv[7]);
        } else {
            uint4 o;
            o.x = (unsigned)f2b(rv[0]) | ((unsigned)f2b(rv[1]) << 16);
            o.y = (unsigned)f2b(rv[2]) | ((unsigned)f2b(rv[3]) << 16);
            o.z = (unsigned)f2b(rv[4]) | ((unsigned)f2b(rv[5]) << 16);
            o.w = (unsigned)f2b(rv[6]) | ((unsigned)f2b(rv[7]) << 16);
            *(uint4*)((char*)outv + (((unsigned)node << 8) | poff)) = o;
        }
    }
}

extern "C" void kernel_launch(void* const* d_in, const int* in_sizes, int n_in,
                              void* d_out, int out_size, void* d_ws, size_t ws_size,
                              hipStream_t stream) {
    const float* feat = (const float*)d_in[0];
    const int*   edges = (const int*)d_in[1];
    const float* W1 = (const float*)d_in[2];
    const float* b1 = (const float*)d_in[3];
    const float* W2 = (const float*)d_in[4];
    const float* b2 = (const float*)d_in[5];
    float* out = (float*)d_out;

    const int N = in_sizes[0] / 128;
    const int E = in_sizes[1] / 2;
    const int* src = edges;
    const int* dst = edges + E;
    const int B = (N + (1 << BSHIFT) - 1) >> BSHIFT;

    // Workspace:
    //   T1: N*128 bf16 (y1 = feat@W1; later y2 = h1@W2)
    //   T2: N*128 bf16 (pairs alias during CSR build; then h1)
    //   Wt1, Wt2, offsets[N], degs[N], bcursor[512], csr[B*CAPB]
    unsigned short* T1  = (unsigned short*)d_ws;
    unsigned short* T2  = T1 + (size_t)N * 128;
    unsigned*       pairs = (unsigned*)T2;
    unsigned short* Wt1 = T2 + (size_t)N * 128;
    unsigned short* Wt2 = Wt1 + 128 * 128;
    int* offsets = (int*)(Wt2 + 128 * 128);
    int* degs    = offsets + ((N + 8) & ~7);
    int* bcursor = degs + ((N + 8) & ~7);
    int* csr     = bcursor + 512;

    const int gemmGrid = (N + 127) / 128;
    const int aggGrid  = (N + 3) / 4;
    const int scGrid   = (E + SCCH - 1) / SCCH;

    // bcursor zero (2 KB)
    hipMemsetAsync(bcursor, 0, (size_t)BMAX * sizeof(int), stream);
    // edge partition into static bucket regions + W transpose (tail blocks)
    bscatter_kernel<<<scGrid + 16, 1024, 0, stream>>>(src, dst, bcursor, pairs,
                                                      W1, W2, Wt1, Wt2,
                                                      E, B, scGrid);
    // y1 = feat(fp32) @ W1
    gemm_xw<true><<<gemmGrid, 256, 0, stream>>>(feat, Wt1, T1, N);
    // per-bucket sort -> offsets/degs/csr
    bfinal_kernel<<<B, 1024, 0, stream>>>(pairs, bcursor, offsets, degs, csr, N);
    // h1 = leaky(L(y1) + b1)  (bf16, overwrites pairs region)
    agg_apply<false><<<aggGrid, 256, 0, stream>>>(T1, offsets, degs, csr, b1,
                                                  (void*)T2, N);
    // y2 = h1 @ W2
    gemm_xw<false><<<gemmGrid, 256, 0, stream>>>(T2, Wt2, T1, N);
    // out = leaky(L(y2) + b2)  (fp32)
    agg_apply<true><<<aggGrid, 256, 0, stream>>>(T1, offsets, degs, csr, b2,
                                                 (void*)out, N);
}